// Round 5
// baseline (418.053 us; speedup 1.0000x reference)
//
#include <hip/hip_runtime.h>
#include <hip/hip_bf16.h>

#define B_ 8
#define G_ 256
#define N_ 1024
#define P_ 4
#define F_ 256
#define KHOP 4
#define KG_ (KHOP * G_)   // 1024

typedef unsigned short ushort_t;
typedef __bf16 bf16x8 __attribute__((ext_vector_type(8)));
typedef unsigned short u16x8 __attribute__((ext_vector_type(8)));
typedef float f32x4 __attribute__((ext_vector_type(4)));

__device__ __forceinline__ unsigned short f2bf(float f) {
  union { float fl; unsigned int i; } v; v.fl = f;
  return (unsigned short)((v.i + 0x7fffu + ((v.i >> 16) & 1u)) >> 16);
}

__device__ __forceinline__ void gload_lds16(const ushort_t* g, ushort_t* l) {
  __builtin_amdgcn_global_load_lds(
      (const __attribute__((address_space(1))) void*)g,
      (__attribute__((address_space(3))) void*)l, 16, 0, 0);
}

// ---------------------------------------------------------------------------
// K1: w1[p,g] = sum_f mixer[p,f]*weight[p,f,g]; w2 with mixer[p,F+f].
__global__ void k_w(const float* __restrict__ mixer, const float* __restrict__ weight,
                    const float* __restrict__ wb, float* __restrict__ w1,
                    float* __restrict__ w2, float* __restrict__ cbuf) {
  int p = blockIdx.x;
  int g = threadIdx.x;
  float acc1 = 0.f, acc2 = 0.f;
  for (int f = 0; f < F_; ++f) {
    float wv = weight[(size_t)(p * F_ + f) * G_ + g];
    acc1 += mixer[p * 2 * F_ + f] * wv;
    acc2 += mixer[p * 2 * F_ + F_ + f] * wv;
  }
  w1[p * G_ + g] = acc1;
  w2[p * G_ + g] = acc2;
  if (g == 0) {
    float c1 = 0.f, c2 = 0.f;
    for (int f = 0; f < F_; ++f) {
      c1 += mixer[p * 2 * F_ + f] * wb[p * F_ + f];
      c2 += mixer[p * 2 * F_ + F_ + f] * wb[p * F_ + f];
    }
    cbuf[2 * p] = c1;
    cbuf[2 * p + 1] = c2;
  }
}

// ---------------------------------------------------------------------------
// K2: e1[b,p,n] = c1[p] + sum_g w1[p,g]*x[b,g,n]; e2 likewise.
__global__ void k_e(const float* __restrict__ x, const float* __restrict__ w1,
                    const float* __restrict__ w2, const float* __restrict__ cbuf,
                    float* __restrict__ e1, float* __restrict__ e2) {
  __shared__ float s1[G_], s2[G_];
  int bp = blockIdx.x >> 2;
  int nc = blockIdx.x & 3;
  int b = bp >> 2, p = bp & (P_ - 1);
  int n = nc * 256 + threadIdx.x;
  s1[threadIdx.x] = w1[p * G_ + threadIdx.x];
  s2[threadIdx.x] = w2[p * G_ + threadIdx.x];
  __syncthreads();
  const float* xb = x + (size_t)b * G_ * N_ + n;
  float a1 = 0.f, a2 = 0.f;
#pragma unroll 8
  for (int g = 0; g < G_; ++g) {
    float xv = xb[(size_t)g * N_];
    a1 = fmaf(s1[g], xv, a1);
    a2 = fmaf(s2[g], xv, a2);
  }
  e1[(size_t)bp * N_ + n] = cbuf[2 * p] + a1;
  e2[(size_t)bp * N_ + n] = cbuf[2 * p + 1] + a2;
}

// ---------------------------------------------------------------------------
// K3: fp32 -> bf16 cast, 4 elems/thread (for filterWeight)
__global__ void k_cvt4(const float* __restrict__ in, ushort_t* __restrict__ out) {
  int i = (blockIdx.x * 256 + threadIdx.x) * 4;
  float4 v = *(const float4*)&in[i];
  ushort4 o;
  o.x = f2bf(v.x); o.y = f2bf(v.y); o.z = f2bf(v.z); o.w = f2bf(v.w);
  *(ushort4*)&out[i] = o;
}

// ---------------------------------------------------------------------------
// K4: xT[b][n][g] = bf16(x[b][g][n])   (64x64 tiles via LDS)
__global__ __launch_bounds__(256) void k_xT(const float* __restrict__ x,
                                            ushort_t* __restrict__ xT) {
  __shared__ ushort_t tile[64][66];
  int b = blockIdx.z;
  int g0 = blockIdx.y * 64;
  int n0 = blockIdx.x * 64;
  int t = threadIdx.x;
  int rr = t >> 4, cc = (t & 15) * 4;
#pragma unroll
  for (int ps = 0; ps < 4; ++ps) {
    float4 v = *(const float4*)&x[((size_t)b * G_ + g0 + ps * 16 + rr) * N_ + n0 + cc];
    tile[ps * 16 + rr][cc] = f2bf(v.x);
    tile[ps * 16 + rr][cc + 1] = f2bf(v.y);
    tile[ps * 16 + rr][cc + 2] = f2bf(v.z);
    tile[ps * 16 + rr][cc + 3] = f2bf(v.w);
  }
  __syncthreads();
#pragma unroll
  for (int ps = 0; ps < 4; ++ps) {
    int nl = ps * 16 + rr;
    int gl = cc;
    ushort4 o;
    o.x = tile[gl][nl];
    o.y = tile[gl + 1][nl];
    o.z = tile[gl + 2][nl];
    o.w = tile[gl + 3][nl];
    *(ushort4*)&xT[((size_t)b * N_ + n0 + nl) * G_ + g0 + gl] = o;
  }
}

// ---------------------------------------------------------------------------
// K5: attention, UNNORMALIZED, p-merged. One block per (b, 64-i-tile, 256-j-tile).
// Reads the S tile once (mask bits -> registers), then for each p in 0..3:
// computes E[i,j] = m ? exp(lrelu(e1[j]+e2[i])) : 0, accumulates row sums
// (-> partial[]), stages the 64x256 tile in LDS, dumps transposed expT[j][i].
// Normalization (1/rowsum) is applied later in the GEMM epilogues (algebra:
// xk . aij = (xk (.) inv) . E).
__global__ __launch_bounds__(256) void k_att(const float* __restrict__ e1,
                                             const float* __restrict__ e2,
                                             const float* __restrict__ S,
                                             ushort_t* __restrict__ expT,
                                             float* __restrict__ partial) {
  __shared__ float se1[4][256];
  __shared__ float se2[4][64];
  __shared__ ushort_t tile[64][260];   // [i-local][j-local], padded
  int b = blockIdx.z;
  int i0 = blockIdx.y * 64;
  int jt = blockIdx.x;
  int j0 = jt * 256;
  int t = threadIdx.x;
  int rr = t >> 4;          // 0..15
  int cc4 = t & 15;
  int cc = cc4 * 4;

  {
    int p = t >> 6, sl = (t & 63) * 4;
    *(float4*)&se1[p][sl] = *(const float4*)&e1[(size_t)(b * 4 + p) * N_ + j0 + sl];
    se2[p][t & 63] = e2[(size_t)(b * 4 + p) * N_ + i0 + (t & 63)];
  }
  __syncthreads();

  // --- read S tile once, build mask bits: mbits[js] bit (ps*4+s) ---
  const float* Sb = S + (size_t)b * N_ * N_;
  unsigned int mbits[4];
#pragma unroll
  for (int js = 0; js < 4; ++js) {
    unsigned int bits = 0;
#pragma unroll
    for (int ps = 0; ps < 4; ++ps) {
      int il = ps * 16 + rr;
      float4 s4 = *(const float4*)&Sb[(size_t)(i0 + il) * N_ + j0 + js * 64 + cc];
      if (fabsf(s4.x) > 1e-9f) bits |= 1u << (ps * 4 + 0);
      if (fabsf(s4.y) > 1e-9f) bits |= 1u << (ps * 4 + 1);
      if (fabsf(s4.z) > 1e-9f) bits |= 1u << (ps * 4 + 2);
      if (fabsf(s4.w) > 1e-9f) bits |= 1u << (ps * 4 + 3);
    }
    mbits[js] = bits;
  }

  for (int p = 0; p < 4; ++p) {
    float re2[4];
#pragma unroll
    for (int ps = 0; ps < 4; ++ps) re2[ps] = se2[p][ps * 16 + rr];
    float psum[4] = {0.f, 0.f, 0.f, 0.f};
#pragma unroll
    for (int js = 0; js < 4; ++js) {
      float4 e1q = *(float4*)&se1[p][js * 64 + cc];
      float e1v[4] = {e1q.x, e1q.y, e1q.z, e1q.w};
      unsigned int bits = mbits[js];
#pragma unroll
      for (int ps = 0; ps < 4; ++ps) {
        int il = ps * 16 + rr;
        float vals[4];
#pragma unroll
        for (int s = 0; s < 4; ++s) {
          float v = e1v[s] + re2[ps];
          float l = v >= 0.f ? v : 0.2f * v;
          bool m = (bits >> (ps * 4 + s)) & 1u;
          float e = m ? __expf(l) : 0.f;
          vals[s] = e;
          psum[ps] += e;
        }
        ushort4 o;
        o.x = f2bf(vals[0]); o.y = f2bf(vals[1]); o.z = f2bf(vals[2]); o.w = f2bf(vals[3]);
        *(ushort4*)&tile[il][js * 64 + cc] = o;
      }
    }
    // row-sum reduce across the 16 lanes sharing each row group
#pragma unroll
    for (int mask = 1; mask < 16; mask <<= 1) {
#pragma unroll
      for (int ps = 0; ps < 4; ++ps) psum[ps] += __shfl_xor(psum[ps], mask, 64);
    }
    if (cc4 == 0) {
#pragma unroll
      for (int ps = 0; ps < 4; ++ps)
        partial[((size_t)(b * 4 + p) * 4 + jt) * N_ + i0 + ps * 16 + rr] = psum[ps];
    }
    __syncthreads();   // tile fully written
    // dump transposed: expT[bp][j0+jl][i0 + 0..63]
    ushort_t* Tb = expT + (size_t)(b * 4 + p) * N_ * N_;
#pragma unroll
    for (int pass = 0; pass < 16; ++pass) {
      int jl = pass * 16 + rr;
      ushort4 o;
      o.x = tile[cc + 0][jl];
      o.y = tile[cc + 1][jl];
      o.z = tile[cc + 2][jl];
      o.w = tile[cc + 3][jl];
      *(ushort4*)&Tb[(size_t)(j0 + jl) * N_ + i0 + cc] = o;
    }
    __syncthreads();   // tile free for next p
  }
}

// ---------------------------------------------------------------------------
// K5b: inv[bp][i] = 1 / sum_jt partial[bp][jt][i]
__global__ void k_inv(const float* __restrict__ partial, float* __restrict__ inv) {
  int idx = blockIdx.x * 256 + threadIdx.x;   // 0..32767
  int bp = idx >> 10, i = idx & (N_ - 1);
  float s = 0.f;
#pragma unroll
  for (int jt = 0; jt < 4; ++jt) s += partial[((size_t)bp * 4 + jt) * N_ + i];
  inv[(size_t)bp * N_ + i] = 1.f / s;
}

// ---------------------------------------------------------------------------
// K6: Horner step GEMM (NT, MFMA bf16, 64x128 tile, 4 waves, BK=32,
// single-barrier double-buffered K-loop).
//   D[f,n] = [sum_m Aprev[bp][f][m] * expT[bp][n][m]]   (if has_prev)
//          +  sum_g fwbf[p][f][kslice*256+g] * xT[b][n][g]
//   last: out_f32 = lrelu(D + bias[f]);  else out_bf16 = bf16(D * inv[n]).
__global__ __launch_bounds__(256, 4) void gemm_step(
    const ushort_t* __restrict__ Aprev, const ushort_t* __restrict__ Bt,
    const ushort_t* __restrict__ fwbf, const ushort_t* __restrict__ xT,
    const float* __restrict__ bias, const float* __restrict__ inv,
    ushort_t* __restrict__ outb, float* __restrict__ outf,
    int kslice, int has_prev, int last) {
  __shared__ ushort_t As[2][64 * 32];
  __shared__ ushort_t Bs[2][128 * 32];
  int bp = blockIdx.z;
  int p = bp & (P_ - 1), b = bp >> 2;
  int n0 = blockIdx.x * 128, m0 = blockIdx.y * 64;
  int t = threadIdx.x;
  int lane = t & 63;
  int w = t >> 6;
  int lr = lane & 15, quad = lane >> 4;
  int rowL = t >> 2;            // 0..63
  int colL = (t & 3) * 8;       // 0,8,16,24
  int ldsoff = (t & ~63) * 8;   // wave-uniform LDS base (ushort units)

  const ushort_t* A1 = Aprev + (size_t)bp * (F_ * N_) + (size_t)(m0 + rowL) * N_ + colL;
  const ushort_t* B1 = Bt + (size_t)bp * N_ * N_ + (size_t)(n0 + rowL) * N_ + colL;
  const ushort_t* A2 = fwbf + (size_t)p * (F_ * KG_) + (size_t)(m0 + rowL) * KG_ +
                       kslice * G_ + colL;
  const ushort_t* B2 = xT + (size_t)b * (N_ * G_) + (size_t)(n0 + rowL) * G_ + colL;
  int npc = has_prev ? 32 : 0;
  int nch = npc + 8;

  auto load_chunk = [&](int ci, int buf) {
    ushort_t* as = &As[buf][ldsoff];
    ushort_t* bs0 = &Bs[buf][ldsoff];
    ushort_t* bs1 = &Bs[buf][2048 + ldsoff];
    if (ci < npc) {
      gload_lds16(A1 + ci * 32, as);
      gload_lds16(B1 + ci * 32, bs0);
      gload_lds16(B1 + (size_t)64 * N_ + ci * 32, bs1);
    } else {
      int cj = (ci - npc) * 32;
      gload_lds16(A2 + cj, as);
      gload_lds16(B2 + cj, bs0);
      gload_lds16(B2 + (size_t)64 * G_ + cj, bs1);
    }
  };

  f32x4 acc[4][2] = {};
  load_chunk(0, 0);
  for (int ci = 0; ci < nch; ++ci) {
    __syncthreads();                       // drains load(ci); frees buf (ci+1)&1
    if (ci + 1 < nch) load_chunk(ci + 1, (ci + 1) & 1);
    int buf = ci & 1;
    bf16x8 af[4], bfr[2];
#pragma unroll
    for (int mi = 0; mi < 4; ++mi)
      af[mi] = __builtin_bit_cast(bf16x8, *(const u16x8*)&As[buf][(mi * 16 + lr) * 32 + quad * 8]);
#pragma unroll
    for (int ni = 0; ni < 2; ++ni)
      bfr[ni] = __builtin_bit_cast(bf16x8, *(const u16x8*)&Bs[buf][(w * 32 + ni * 16 + lr) * 32 + quad * 8]);
#pragma unroll
    for (int mi = 0; mi < 4; ++mi)
#pragma unroll
      for (int ni = 0; ni < 2; ++ni)
        acc[mi][ni] = __builtin_amdgcn_mfma_f32_16x16x32_bf16(af[mi], bfr[ni], acc[mi][ni], 0, 0, 0);
  }

  if (last) {
    float* Ob = outf + (size_t)bp * (F_ * N_);
#pragma unroll
    for (int mi = 0; mi < 4; ++mi) {
      int fbase = m0 + mi * 16 + quad * 4;
#pragma unroll
      for (int ni = 0; ni < 2; ++ni) {
        int n = n0 + w * 32 + ni * 16 + lr;
#pragma unroll
        for (int r = 0; r < 4; ++r) {
          float v = acc[mi][ni][r] + bias[fbase + r];
          Ob[(size_t)(fbase + r) * N_ + n] = v >= 0.f ? v : 0.01f * v;
        }
      }
    }
  } else {
    ushort_t* Ob = outb + (size_t)bp * (F_ * N_);
    float iv[2];
#pragma unroll
    for (int ni = 0; ni < 2; ++ni)
      iv[ni] = inv[(size_t)bp * N_ + n0 + w * 32 + ni * 16 + lr];
#pragma unroll
    for (int mi = 0; mi < 4; ++mi) {
      int fbase = m0 + mi * 16 + quad * 4;
#pragma unroll
      for (int ni = 0; ni < 2; ++ni) {
        int n = n0 + w * 32 + ni * 16 + lr;
#pragma unroll
        for (int r = 0; r < 4; ++r)
          Ob[(size_t)(fbase + r) * N_ + n] = f2bf(acc[mi][ni][r] * iv[ni]);
      }
    }
  }
}

// ---------------------------------------------------------------------------
extern "C" void kernel_launch(void* const* d_in, const int* in_sizes, int n_in,
                              void* d_out, int out_size, void* d_ws, size_t ws_size,
                              hipStream_t stream) {
  const float* x = (const float*)d_in[0];
  const float* mixer = (const float*)d_in[1];
  const float* weight = (const float*)d_in[2];
  const float* wb = (const float*)d_in[3];
  const float* fw = (const float*)d_in[4];
  const float* bias = (const float*)d_in[5];
  const float* S = (const float*)d_in[6];
  float* out = (float*)d_out;

  char* ws = (char*)d_ws;
  size_t off = 0;
  auto take = [&](size_t bytes) -> char* {
    char* p = ws + off;
    off = (off + bytes + 255) & ~(size_t)255;
    return p;
  };
  float* w1 = (float*)take(P_ * G_ * 4);
  float* w2 = (float*)take(P_ * G_ * 4);
  float* cbuf = (float*)take(2 * P_ * 4);
  float* e1 = (float*)take((size_t)B_ * P_ * N_ * 4);
  float* e2 = (float*)take((size_t)B_ * P_ * N_ * 4);
  float* partial = (float*)take((size_t)B_ * P_ * 4 * N_ * 4);
  float* inv = (float*)take((size_t)B_ * P_ * N_ * 4);
  ushort_t* fwbf = (ushort_t*)take((size_t)P_ * F_ * KHOP * G_ * 2);
  ushort_t* xT = (ushort_t*)take((size_t)B_ * N_ * G_ * 2);
  ushort_t* expT = (ushort_t*)take((size_t)B_ * P_ * N_ * N_ * 2);
  ushort_t* sA = (ushort_t*)take((size_t)B_ * P_ * F_ * N_ * 2);
  ushort_t* sB = (ushort_t*)take((size_t)B_ * P_ * F_ * N_ * 2);

  k_w<<<P_, 256, 0, stream>>>(mixer, weight, wb, w1, w2, cbuf);
  k_e<<<B_ * P_ * 4, 256, 0, stream>>>(x, w1, w2, cbuf, e1, e2);
  k_att<<<dim3(4, 16, 8), 256, 0, stream>>>(e1, e2, S, expT, partial);
  k_inv<<<128, 256, 0, stream>>>(partial, inv);
  k_cvt4<<<(P_ * F_ * KHOP * G_) / 1024, 256, 0, stream>>>(fw, fwbf);
  k_xT<<<dim3(16, 4, 8), 256, 0, stream>>>(x, xT);

  dim3 gg(8, 4, 32);
  // Horner (inv folded into stored intermediates):
  // s3' = (fw3*x) . inv ; s2' = (s3'*E^T + fw2*x) . inv ;
  // s1' = (s2'*E^T + fw1*x) . inv ; out = lrelu(s1'*E^T + fw0*x + bias)
  gemm_step<<<gg, 256, 0, stream>>>(nullptr, expT, fwbf, xT, bias, inv, sA, nullptr, 3, 0, 0);
  gemm_step<<<gg, 256, 0, stream>>>(sA, expT, fwbf, xT, bias, inv, sB, nullptr, 2, 1, 0);
  gemm_step<<<gg, 256, 0, stream>>>(sB, expT, fwbf, xT, bias, inv, sA, nullptr, 1, 1, 0);
  gemm_step<<<gg, 256, 0, stream>>>(sA, expT, fwbf, xT, bias, inv, nullptr, out, 0, 1, 1);
}

// Round 6
// 285.193 us; speedup vs baseline: 1.4659x; 1.4659x over previous
//
#include <hip/hip_runtime.h>
#include <hip/hip_bf16.h>

#define B_ 8
#define G_ 256
#define N_ 1024
#define P_ 4
#define F_ 256
#define KHOP 4
#define KG_ (KHOP * G_)   // 1024

typedef unsigned short ushort_t;
typedef __bf16 bf16x8 __attribute__((ext_vector_type(8)));
typedef unsigned short u16x8 __attribute__((ext_vector_type(8)));
typedef float f32x4 __attribute__((ext_vector_type(4)));

__device__ __forceinline__ unsigned short f2bf(float f) {
  union { float fl; unsigned int i; } v; v.fl = f;
  return (unsigned short)((v.i + 0x7fffu + ((v.i >> 16) & 1u)) >> 16);
}

__device__ __forceinline__ void gload_lds16(const ushort_t* g, ushort_t* l) {
  __builtin_amdgcn_global_load_lds(
      (const __attribute__((address_space(1))) void*)g,
      (__attribute__((address_space(3))) void*)l, 16, 0, 0);
}

// ---------------------------------------------------------------------------
// K1: w1[p,g] = sum_f mixer[p,f]*weight[p,f,g]; w2 with mixer[p,F+f].
__global__ void k_w(const float* __restrict__ mixer, const float* __restrict__ weight,
                    const float* __restrict__ wb, float* __restrict__ w1,
                    float* __restrict__ w2, float* __restrict__ cbuf) {
  int p = blockIdx.x;
  int g = threadIdx.x;
  float acc1 = 0.f, acc2 = 0.f;
  for (int f = 0; f < F_; ++f) {
    float wv = weight[(size_t)(p * F_ + f) * G_ + g];
    acc1 += mixer[p * 2 * F_ + f] * wv;
    acc2 += mixer[p * 2 * F_ + F_ + f] * wv;
  }
  w1[p * G_ + g] = acc1;
  w2[p * G_ + g] = acc2;
  if (g == 0) {
    float c1 = 0.f, c2 = 0.f;
    for (int f = 0; f < F_; ++f) {
      c1 += mixer[p * 2 * F_ + f] * wb[p * F_ + f];
      c2 += mixer[p * 2 * F_ + F_ + f] * wb[p * F_ + f];
    }
    cbuf[2 * p] = c1;
    cbuf[2 * p + 1] = c2;
  }
}

// ---------------------------------------------------------------------------
// K2: e1[b,p,n] = c1[p] + sum_g w1[p,g]*x[b,g,n]; e2 likewise.
__global__ void k_e(const float* __restrict__ x, const float* __restrict__ w1,
                    const float* __restrict__ w2, const float* __restrict__ cbuf,
                    float* __restrict__ e1, float* __restrict__ e2) {
  __shared__ float s1[G_], s2[G_];
  int bp = blockIdx.x >> 2;
  int nc = blockIdx.x & 3;
  int b = bp >> 2, p = bp & (P_ - 1);
  int n = nc * 256 + threadIdx.x;
  s1[threadIdx.x] = w1[p * G_ + threadIdx.x];
  s2[threadIdx.x] = w2[p * G_ + threadIdx.x];
  __syncthreads();
  const float* xb = x + (size_t)b * G_ * N_ + n;
  float a1 = 0.f, a2 = 0.f;
#pragma unroll 8
  for (int g = 0; g < G_; ++g) {
    float xv = xb[(size_t)g * N_];
    a1 = fmaf(s1[g], xv, a1);
    a2 = fmaf(s2[g], xv, a2);
  }
  e1[(size_t)bp * N_ + n] = cbuf[2 * p] + a1;
  e2[(size_t)bp * N_ + n] = cbuf[2 * p + 1] + a2;
}

// ---------------------------------------------------------------------------
// K3: fp32 -> bf16 cast, 4 elems/thread (for filterWeight)
__global__ void k_cvt4(const float* __restrict__ in, ushort_t* __restrict__ out) {
  int i = (blockIdx.x * 256 + threadIdx.x) * 4;
  float4 v = *(const float4*)&in[i];
  ushort4 o;
  o.x = f2bf(v.x); o.y = f2bf(v.y); o.z = f2bf(v.z); o.w = f2bf(v.w);
  *(ushort4*)&out[i] = o;
}

// ---------------------------------------------------------------------------
// K4: xT[b][n][g] = bf16(x[b][g][n])   (64x64 tiles via LDS)
__global__ __launch_bounds__(256) void k_xT(const float* __restrict__ x,
                                            ushort_t* __restrict__ xT) {
  __shared__ ushort_t tile[64][66];
  int b = blockIdx.z;
  int g0 = blockIdx.y * 64;
  int n0 = blockIdx.x * 64;
  int t = threadIdx.x;
  int rr = t >> 4, cc = (t & 15) * 4;
#pragma unroll
  for (int ps = 0; ps < 4; ++ps) {
    float4 v = *(const float4*)&x[((size_t)b * G_ + g0 + ps * 16 + rr) * N_ + n0 + cc];
    tile[ps * 16 + rr][cc] = f2bf(v.x);
    tile[ps * 16 + rr][cc + 1] = f2bf(v.y);
    tile[ps * 16 + rr][cc + 2] = f2bf(v.z);
    tile[ps * 16 + rr][cc + 3] = f2bf(v.w);
  }
  __syncthreads();
#pragma unroll
  for (int ps = 0; ps < 4; ++ps) {
    int nl = ps * 16 + rr;
    int gl = cc;
    ushort4 o;
    o.x = tile[gl][nl];
    o.y = tile[gl + 1][nl];
    o.z = tile[gl + 2][nl];
    o.w = tile[gl + 3][nl];
    *(ushort4*)&xT[((size_t)b * N_ + n0 + nl) * G_ + g0 + gl] = o;
  }
}

// ---------------------------------------------------------------------------
// K5: attention, UNNORMALIZED. One block per (jt 256-j-tile, 64-i-tile, bp).
// Computes E[i,j] = m ? exp(lrelu(e1[j]+e2[i])) : 0 into an LDS tile stored
// TRANSPOSED [j][i], accumulates row sums (partial per jt), then dumps the
// tile with vector LDS reads + coalesced 16B global stores. 2 barriers total.
// Normalization (1/rowsum) is applied in the GEMM epilogues (algebra:
// xk . aij = (xk (.) inv) . E).
__global__ __launch_bounds__(256) void k_att(const float* __restrict__ e1,
                                             const float* __restrict__ e2,
                                             const float* __restrict__ S,
                                             ushort_t* __restrict__ expT,
                                             float* __restrict__ partial) {
  __shared__ ushort_t tile[256][72];   // [j-local][i-local], 72 pad (144B rows, 16B-aligned)
  __shared__ float se1[256];
  __shared__ float se2[64];
  int bp = blockIdx.z;
  int b = bp >> 2;
  int i0 = blockIdx.y * 64;
  int jt = blockIdx.x;
  int j0 = jt * 256;
  int t = threadIdx.x;
  int rr = t >> 4;          // 0..15 (lane>>4 within wave = rr&3 pattern ok for shfl)
  int cc4 = t & 15;
  int cc = cc4 * 4;

  se1[t] = e1[(size_t)bp * N_ + j0 + t];
  if (t < 64) se2[t] = e2[(size_t)bp * N_ + i0 + t];
  __syncthreads();

  const float* Sb = S + (size_t)b * N_ * N_;
  float re2[4];
#pragma unroll
  for (int ps = 0; ps < 4; ++ps) re2[ps] = se2[ps * 16 + rr];
  float psum[4] = {0.f, 0.f, 0.f, 0.f};
#pragma unroll
  for (int js = 0; js < 4; ++js) {
    float4 e1q = *(float4*)&se1[js * 64 + cc];
    float e1v[4] = {e1q.x, e1q.y, e1q.z, e1q.w};
#pragma unroll
    for (int ps = 0; ps < 4; ++ps) {
      int il = ps * 16 + rr;
      float4 s4 = *(const float4*)&Sb[(size_t)(i0 + il) * N_ + j0 + js * 64 + cc];
      float sv[4] = {s4.x, s4.y, s4.z, s4.w};
#pragma unroll
      for (int s = 0; s < 4; ++s) {
        float v = e1v[s] + re2[ps];
        float l = v >= 0.f ? v : 0.2f * v;
        bool m = fabsf(sv[s]) > 1e-9f;
        float e = m ? __expf(l) : 0.f;
        psum[ps] += e;
        tile[js * 64 + cc + s][il] = f2bf(e);
      }
    }
  }
  // reduce psum across the 16 lanes (cc4 dim) sharing each row
#pragma unroll
  for (int mask = 1; mask < 16; mask <<= 1) {
#pragma unroll
    for (int ps = 0; ps < 4; ++ps) psum[ps] += __shfl_xor(psum[ps], mask, 64);
  }
  if (cc4 == 0) {
#pragma unroll
    for (int ps = 0; ps < 4; ++ps)
      partial[((size_t)bp * 4 + jt) * N_ + i0 + ps * 16 + rr] = psum[ps];
  }
  __syncthreads();
  // dump: vector LDS read + 16B coalesced store
  ushort_t* Tb = expT + (size_t)bp * N_ * N_;
  int jl0 = t >> 3;         // 0..31
  int ig = (t & 7) * 8;     // 0..56
#pragma unroll
  for (int pass = 0; pass < 8; ++pass) {
    int jl = pass * 32 + jl0;
    u16x8 v = *(const u16x8*)&tile[jl][ig];
    *(u16x8*)&Tb[(size_t)(j0 + jl) * N_ + i0 + ig] = v;
  }
}

// ---------------------------------------------------------------------------
// K5b: inv[bp][i] = 1 / sum_jt partial[bp][jt][i]
__global__ void k_inv(const float* __restrict__ partial, float* __restrict__ inv) {
  int idx = blockIdx.x * 256 + threadIdx.x;   // 0..32767
  int bp = idx >> 10, i = idx & (N_ - 1);
  float s = 0.f;
#pragma unroll
  for (int jt = 0; jt < 4; ++jt) s += partial[((size_t)bp * 4 + jt) * N_ + i];
  inv[(size_t)bp * N_ + i] = 1.f / s;
}

// ---------------------------------------------------------------------------
// K6: Horner step GEMM (NT, MFMA bf16, 128x128 tile, 4 waves, BK=64,
// R4-style 2-barrier rhythm: sync -> issue 8 gloads -> sync -> 32 MFMA/wave).
//   D[f,n] = [sum_m Aprev[bp][f][m] * expT[bp][n][m]]   (if has_prev)
//          +  sum_g fwbf[p][f][kslice*256+g] * xT[b][n][g]
//   last: out_f32 = lrelu(D + bias[f]);  else out_bf16 = bf16(D * inv[n]).
__global__ __launch_bounds__(256, 2) void gemm_step(
    const ushort_t* __restrict__ Aprev, const ushort_t* __restrict__ Bt,
    const ushort_t* __restrict__ fwbf, const ushort_t* __restrict__ xT,
    const float* __restrict__ bias, const float* __restrict__ inv,
    ushort_t* __restrict__ outb, float* __restrict__ outf,
    int kslice, int has_prev, int last) {
  __shared__ ushort_t As[2][128 * 32];
  __shared__ ushort_t Bs[2][128 * 32];
  int bp = blockIdx.z;
  int p = bp & (P_ - 1), b = bp >> 2;
  int n0 = blockIdx.x * 128, m0 = blockIdx.y * 128;
  int t = threadIdx.x;
  int lane = t & 63;
  int w = t >> 6;
  int wm = w >> 1, wn = w & 1;
  int lr = lane & 15, quad = lane >> 4;
  int rowL = t >> 2;            // 0..63
  int colL = (t & 3) * 8;       // 0,8,16,24
  int ldsoff = (t & ~63) * 8;   // wave-uniform LDS base (ushort units)

  const ushort_t* A1 = Aprev + (size_t)bp * (F_ * N_) + (size_t)(m0 + rowL) * N_ + colL;
  const ushort_t* B1 = Bt + (size_t)bp * N_ * N_ + (size_t)(n0 + rowL) * N_ + colL;
  const ushort_t* A2 = fwbf + (size_t)p * (F_ * KG_) + (size_t)(m0 + rowL) * KG_ +
                       kslice * G_ + colL;
  const ushort_t* B2 = xT + (size_t)b * (N_ * G_) + (size_t)(n0 + rowL) * G_ + colL;

  f32x4 acc[4][4] = {};

  if (has_prev) {
    for (int kt = 0; kt < N_; kt += 64) {
      __syncthreads();
      gload_lds16(A1 + kt, &As[0][ldsoff]);
      gload_lds16(A1 + (size_t)64 * N_ + kt, &As[0][2048 + ldsoff]);
      gload_lds16(A1 + kt + 32, &As[1][ldsoff]);
      gload_lds16(A1 + (size_t)64 * N_ + kt + 32, &As[1][2048 + ldsoff]);
      gload_lds16(B1 + kt, &Bs[0][ldsoff]);
      gload_lds16(B1 + (size_t)64 * N_ + kt, &Bs[0][2048 + ldsoff]);
      gload_lds16(B1 + kt + 32, &Bs[1][ldsoff]);
      gload_lds16(B1 + (size_t)64 * N_ + kt + 32, &Bs[1][2048 + ldsoff]);
      __syncthreads();
#pragma unroll
      for (int c = 0; c < 2; ++c) {
        bf16x8 af[4], bfr[4];
#pragma unroll
        for (int mi = 0; mi < 4; ++mi)
          af[mi] = __builtin_bit_cast(bf16x8,
              *(const u16x8*)&As[c][(wm * 64 + mi * 16 + lr) * 32 + quad * 8]);
#pragma unroll
        for (int ni = 0; ni < 4; ++ni)
          bfr[ni] = __builtin_bit_cast(bf16x8,
              *(const u16x8*)&Bs[c][(wn * 64 + ni * 16 + lr) * 32 + quad * 8]);
#pragma unroll
        for (int mi = 0; mi < 4; ++mi)
#pragma unroll
          for (int ni = 0; ni < 4; ++ni)
            acc[mi][ni] = __builtin_amdgcn_mfma_f32_16x16x32_bf16(af[mi], bfr[ni], acc[mi][ni], 0, 0, 0);
      }
    }
  }
  for (int gt = 0; gt < G_; gt += 64) {
    __syncthreads();
    gload_lds16(A2 + gt, &As[0][ldsoff]);
    gload_lds16(A2 + (size_t)64 * KG_ + gt, &As[0][2048 + ldsoff]);
    gload_lds16(A2 + gt + 32, &As[1][ldsoff]);
    gload_lds16(A2 + (size_t)64 * KG_ + gt + 32, &As[1][2048 + ldsoff]);
    gload_lds16(B2 + gt, &Bs[0][ldsoff]);
    gload_lds16(B2 + (size_t)64 * G_ + gt, &Bs[0][2048 + ldsoff]);
    gload_lds16(B2 + gt + 32, &Bs[1][ldsoff]);
    gload_lds16(B2 + (size_t)64 * G_ + gt + 32, &Bs[1][2048 + ldsoff]);
    __syncthreads();
#pragma unroll
    for (int c = 0; c < 2; ++c) {
      bf16x8 af[4], bfr[4];
#pragma unroll
      for (int mi = 0; mi < 4; ++mi)
        af[mi] = __builtin_bit_cast(bf16x8,
            *(const u16x8*)&As[c][(wm * 64 + mi * 16 + lr) * 32 + quad * 8]);
#pragma unroll
      for (int ni = 0; ni < 4; ++ni)
        bfr[ni] = __builtin_bit_cast(bf16x8,
            *(const u16x8*)&Bs[c][(wn * 64 + ni * 16 + lr) * 32 + quad * 8]);
#pragma unroll
      for (int mi = 0; mi < 4; ++mi)
#pragma unroll
        for (int ni = 0; ni < 4; ++ni)
          acc[mi][ni] = __builtin_amdgcn_mfma_f32_16x16x32_bf16(af[mi], bfr[ni], acc[mi][ni], 0, 0, 0);
    }
  }

  if (last) {
    float* Ob = outf + (size_t)bp * (F_ * N_);
#pragma unroll
    for (int mi = 0; mi < 4; ++mi) {
      int fbase = m0 + wm * 64 + mi * 16 + quad * 4;
#pragma unroll
      for (int ni = 0; ni < 4; ++ni) {
        int n = n0 + wn * 64 + ni * 16 + lr;
#pragma unroll
        for (int r = 0; r < 4; ++r) {
          float v = acc[mi][ni][r] + bias[fbase + r];
          Ob[(size_t)(fbase + r) * N_ + n] = v >= 0.f ? v : 0.01f * v;
        }
      }
    }
  } else {
    ushort_t* Ob = outb + (size_t)bp * (F_ * N_);
    float iv[4];
#pragma unroll
    for (int ni = 0; ni < 4; ++ni)
      iv[ni] = inv[(size_t)bp * N_ + n0 + wn * 64 + ni * 16 + lr];
#pragma unroll
    for (int mi = 0; mi < 4; ++mi) {
      int fbase = m0 + wm * 64 + mi * 16 + quad * 4;
#pragma unroll
      for (int ni = 0; ni < 4; ++ni) {
        int n = n0 + wn * 64 + ni * 16 + lr;
#pragma unroll
        for (int r = 0; r < 4; ++r)
          Ob[(size_t)(fbase + r) * N_ + n] = f2bf(acc[mi][ni][r] * iv[ni]);
      }
    }
  }
}

// ---------------------------------------------------------------------------
extern "C" void kernel_launch(void* const* d_in, const int* in_sizes, int n_in,
                              void* d_out, int out_size, void* d_ws, size_t ws_size,
                              hipStream_t stream) {
  const float* x = (const float*)d_in[0];
  const float* mixer = (const float*)d_in[1];
  const float* weight = (const float*)d_in[2];
  const float* wb = (const float*)d_in[3];
  const float* fw = (const float*)d_in[4];
  const float* bias = (const float*)d_in[5];
  const float* S = (const float*)d_in[6];
  float* out = (float*)d_out;

  char* ws = (char*)d_ws;
  size_t off = 0;
  auto take = [&](size_t bytes) -> char* {
    char* p = ws + off;
    off = (off + bytes + 255) & ~(size_t)255;
    return p;
  };
  float* w1 = (float*)take(P_ * G_ * 4);
  float* w2 = (float*)take(P_ * G_ * 4);
  float* cbuf = (float*)take(2 * P_ * 4);
  float* e1 = (float*)take((size_t)B_ * P_ * N_ * 4);
  float* e2 = (float*)take((size_t)B_ * P_ * N_ * 4);
  float* partial = (float*)take((size_t)B_ * P_ * 4 * N_ * 4);
  float* inv = (float*)take((size_t)B_ * P_ * N_ * 4);
  ushort_t* fwbf = (ushort_t*)take((size_t)P_ * F_ * KHOP * G_ * 2);
  ushort_t* xT = (ushort_t*)take((size_t)B_ * N_ * G_ * 2);
  ushort_t* expT = (ushort_t*)take((size_t)B_ * P_ * N_ * N_ * 2);
  ushort_t* sA = (ushort_t*)take((size_t)B_ * P_ * F_ * N_ * 2);
  ushort_t* sB = (ushort_t*)take((size_t)B_ * P_ * F_ * N_ * 2);

  k_w<<<P_, 256, 0, stream>>>(mixer, weight, wb, w1, w2, cbuf);
  k_e<<<B_ * P_ * 4, 256, 0, stream>>>(x, w1, w2, cbuf, e1, e2);
  k_att<<<dim3(4, 16, 32), 256, 0, stream>>>(e1, e2, S, expT, partial);
  k_inv<<<128, 256, 0, stream>>>(partial, inv);
  k_cvt4<<<(P_ * F_ * KHOP * G_) / 1024, 256, 0, stream>>>(fw, fwbf);
  k_xT<<<dim3(16, 4, 8), 256, 0, stream>>>(x, xT);

  dim3 gg(8, 2, 32);
  // Horner (inv folded into stored intermediates):
  // s3' = (fw3*x) . inv ; s2' = (s3'*E^T + fw2*x) . inv ;
  // s1' = (s2'*E^T + fw1*x) . inv ; out = lrelu(s1'*E^T + fw0*x + bias)
  gemm_step<<<gg, 256, 0, stream>>>(nullptr, expT, fwbf, xT, bias, inv, sA, nullptr, 3, 0, 0);
  gemm_step<<<gg, 256, 0, stream>>>(sA, expT, fwbf, xT, bias, inv, sB, nullptr, 2, 1, 0);
  gemm_step<<<gg, 256, 0, stream>>>(sB, expT, fwbf, xT, bias, inv, sA, nullptr, 1, 1, 0);
  gemm_step<<<gg, 256, 0, stream>>>(sA, expT, fwbf, xT, bias, inv, nullptr, out, 0, 1, 1);
}

// Round 7
// 256.415 us; speedup vs baseline: 1.6304x; 1.1122x over previous
//
#include <hip/hip_runtime.h>
#include <hip/hip_bf16.h>

#define B_ 8
#define G_ 256
#define N_ 1024
#define P_ 4
#define F_ 256
#define KHOP 4
#define KG_ (KHOP * G_)   // 1024

typedef unsigned short ushort_t;
typedef __bf16 bf16x8 __attribute__((ext_vector_type(8)));
typedef unsigned short u16x8 __attribute__((ext_vector_type(8)));
typedef float f32x4 __attribute__((ext_vector_type(4)));

__device__ __forceinline__ unsigned short f2bf(float f) {
  union { float fl; unsigned int i; } v; v.fl = f;
  return (unsigned short)((v.i + 0x7fffu + ((v.i >> 16) & 1u)) >> 16);
}

__device__ __forceinline__ void gload_lds16(const ushort_t* g, ushort_t* l) {
  __builtin_amdgcn_global_load_lds(
      (const __attribute__((address_space(1))) void*)g,
      (__attribute__((address_space(3))) void*)l, 16, 0, 0);
}

// ---------------------------------------------------------------------------
// K-PREP: one kernel, block-range partitioned.
//   blocks [0,128):    e1/e2 (recomputes w1/w2 in LDS per block - trivial)
//   blocks [128,1152): filterWeight fp32->bf16
//   blocks [1152,1664): xT[b][n][g] = bf16(x[b][g][n])
//   blocks [1664,1792): zero sumb
__global__ __launch_bounds__(256) void k_prep(
    const float* __restrict__ x, const float* __restrict__ mixer,
    const float* __restrict__ weight, const float* __restrict__ wb,
    const float* __restrict__ fw, float* __restrict__ e1, float* __restrict__ e2,
    ushort_t* __restrict__ fwbf, ushort_t* __restrict__ xT,
    float* __restrict__ sumb) {
  int blk = blockIdx.x;
  int t = threadIdx.x;
  if (blk < 128) {
    // ---- e-part: bp = blk>>2 covers n-chunk (blk&3)*256 ----
    __shared__ float s1[G_], s2[G_];
    __shared__ float cred[2][4];
    int bp = blk >> 2;
    int nc = blk & 3;
    int b = bp >> 2, p = bp & (P_ - 1);
    int n = nc * 256 + t;
    // w1/w2 for this p, one g per thread
    float acc1 = 0.f, acc2 = 0.f;
    const float* wp = weight + (size_t)p * F_ * G_ + t;
    const float* mp = mixer + p * 2 * F_;
    for (int f = 0; f < F_; ++f) {
      float wv = wp[(size_t)f * G_];
      acc1 = fmaf(mp[f], wv, acc1);
      acc2 = fmaf(mp[F_ + f], wv, acc2);
    }
    s1[t] = acc1;
    s2[t] = acc2;
    // c1/c2 = mixer . wb  (wb is zeros in data, but exact)
    float c1p = mp[t] * wb[p * F_ + t];
    float c2p = mp[F_ + t] * wb[p * F_ + t];
#pragma unroll
    for (int mask = 1; mask < 64; mask <<= 1) {
      c1p += __shfl_xor(c1p, mask, 64);
      c2p += __shfl_xor(c2p, mask, 64);
    }
    if ((t & 63) == 0) {
      cred[0][t >> 6] = c1p;
      cred[1][t >> 6] = c2p;
    }
    __syncthreads();
    float c1 = cred[0][0] + cred[0][1] + cred[0][2] + cred[0][3];
    float c2 = cred[1][0] + cred[1][1] + cred[1][2] + cred[1][3];
    const float* xb = x + (size_t)b * G_ * N_ + n;
    float a1 = 0.f, a2 = 0.f;
#pragma unroll 8
    for (int g = 0; g < G_; ++g) {
      float xv = xb[(size_t)g * N_];
      a1 = fmaf(s1[g], xv, a1);
      a2 = fmaf(s2[g], xv, a2);
    }
    e1[(size_t)bp * N_ + n] = c1 + a1;
    e2[(size_t)bp * N_ + n] = c2 + a2;
  } else if (blk < 128 + 1024) {
    // ---- filterWeight cast ----
    int i = (blk - 128) * 1024 + t * 4;
    float4 v = *(const float4*)&fw[i];
    ushort4 o;
    o.x = f2bf(v.x); o.y = f2bf(v.y); o.z = f2bf(v.z); o.w = f2bf(v.w);
    *(ushort4*)&fwbf[i] = o;
  } else if (blk < 1152 + 512) {
    // ---- xT transpose+cast ----
    __shared__ ushort_t tile[64][66];
    int idx = blk - 1152;
    int n0 = (idx & 15) * 64;
    int g0 = ((idx >> 4) & 3) * 64;
    int b = idx >> 6;
    int rr = t >> 4, cc = (t & 15) * 4;
#pragma unroll
    for (int ps = 0; ps < 4; ++ps) {
      float4 v = *(const float4*)&x[((size_t)b * G_ + g0 + ps * 16 + rr) * N_ + n0 + cc];
      tile[ps * 16 + rr][cc] = f2bf(v.x);
      tile[ps * 16 + rr][cc + 1] = f2bf(v.y);
      tile[ps * 16 + rr][cc + 2] = f2bf(v.z);
      tile[ps * 16 + rr][cc + 3] = f2bf(v.w);
    }
    __syncthreads();
#pragma unroll
    for (int ps = 0; ps < 4; ++ps) {
      int nl = ps * 16 + rr;
      int gl = cc;
      ushort4 o;
      o.x = tile[gl][nl];
      o.y = tile[gl + 1][nl];
      o.z = tile[gl + 2][nl];
      o.w = tile[gl + 3][nl];
      *(ushort4*)&xT[((size_t)b * N_ + n0 + nl) * G_ + g0 + gl] = o;
    }
  } else {
    // ---- zero sumb (32*1024 floats) ----
    int i = (blk - 1664) * 256 + t;
    sumb[i] = 0.f;
  }
}

// ---------------------------------------------------------------------------
// K5: attention, UNNORMALIZED. One block per (jt 256-j-tile, 64-i-tile, bp).
// Computes E[i,j] = m ? exp(lrelu(e1[j]+e2[i])) : 0 into an LDS tile stored
// TRANSPOSED [j][i], atomically accumulates row sums into sumb, then dumps
// the tile with vector LDS reads + coalesced 16B global stores.
// Normalization (1/rowsum) is applied in the GEMM epilogues (algebra:
// xk . aij = (xk (.) inv) . E).
__global__ __launch_bounds__(256) void k_att(const float* __restrict__ e1,
                                             const float* __restrict__ e2,
                                             const float* __restrict__ S,
                                             ushort_t* __restrict__ expT,
                                             float* __restrict__ sumb) {
  __shared__ ushort_t tile[256][72];   // [j-local][i-local]
  __shared__ float se1[256];
  __shared__ float se2[64];
  int bp = blockIdx.z;
  int b = bp >> 2;
  int i0 = blockIdx.y * 64;
  int jt = blockIdx.x;
  int j0 = jt * 256;
  int t = threadIdx.x;
  int rr = t >> 4;
  int cc4 = t & 15;
  int cc = cc4 * 4;

  se1[t] = e1[(size_t)bp * N_ + j0 + t];
  if (t < 64) se2[t] = e2[(size_t)bp * N_ + i0 + t];
  __syncthreads();

  const float* Sb = S + (size_t)b * N_ * N_;
  float re2[4];
#pragma unroll
  for (int ps = 0; ps < 4; ++ps) re2[ps] = se2[ps * 16 + rr];
  float psum[4] = {0.f, 0.f, 0.f, 0.f};
#pragma unroll
  for (int js = 0; js < 4; ++js) {
    float4 e1q = *(float4*)&se1[js * 64 + cc];
    float e1v[4] = {e1q.x, e1q.y, e1q.z, e1q.w};
#pragma unroll
    for (int ps = 0; ps < 4; ++ps) {
      int il = ps * 16 + rr;
      float4 s4 = *(const float4*)&Sb[(size_t)(i0 + il) * N_ + j0 + js * 64 + cc];
      float sv[4] = {s4.x, s4.y, s4.z, s4.w};
#pragma unroll
      for (int s = 0; s < 4; ++s) {
        float v = e1v[s] + re2[ps];
        float l = v >= 0.f ? v : 0.2f * v;
        bool m = fabsf(sv[s]) > 1e-9f;
        float e = m ? __expf(l) : 0.f;
        psum[ps] += e;
        tile[js * 64 + cc + s][il] = f2bf(e);
      }
    }
  }
  // reduce psum across the 16 lanes (cc4 dim) sharing each row, then atomic
#pragma unroll
  for (int mask = 1; mask < 16; mask <<= 1) {
#pragma unroll
    for (int ps = 0; ps < 4; ++ps) psum[ps] += __shfl_xor(psum[ps], mask, 64);
  }
  if (cc4 == 0) {
#pragma unroll
    for (int ps = 0; ps < 4; ++ps)
      atomicAdd(&sumb[(size_t)bp * N_ + i0 + ps * 16 + rr], psum[ps]);
  }
  __syncthreads();
  // dump: vector LDS read + 16B coalesced store
  ushort_t* Tb = expT + (size_t)bp * N_ * N_;
  int jl0 = t >> 3;         // 0..31
  int ig = (t & 7) * 8;     // 0..56
#pragma unroll
  for (int pass = 0; pass < 8; ++pass) {
    int jl = pass * 32 + jl0;
    u16x8 v = *(const u16x8*)&tile[jl][ig];
    *(u16x8*)&Tb[(size_t)(j0 + jl) * N_ + i0 + ig] = v;
  }
}

// ---------------------------------------------------------------------------
// K6: Horner step GEMM (NT, MFMA bf16, 128x128 tile, 4 waves, BK=64,
// 2-barrier rhythm: sync -> issue 8 gloads -> sync -> 32 MFMA/wave).
//   D[f,n] = [sum_m Aprev[bp][f][m] * expT[bp][n][m]]   (if has_prev)
//          +  sum_g fwbf[p][f][kslice*256+g] * xT[b][n][g]
//   last: out_f32 = lrelu(D + bias[f]);  else out_bf16 = bf16(D / sumb[n]).
__global__ __launch_bounds__(256, 2) void gemm_step(
    const ushort_t* __restrict__ Aprev, const ushort_t* __restrict__ Bt,
    const ushort_t* __restrict__ fwbf, const ushort_t* __restrict__ xT,
    const float* __restrict__ bias, const float* __restrict__ sumb,
    ushort_t* __restrict__ outb, float* __restrict__ outf,
    int kslice, int has_prev, int last) {
  __shared__ ushort_t As[2][128 * 32];
  __shared__ ushort_t Bs[2][128 * 32];
  int bp = blockIdx.z;
  int p = bp & (P_ - 1), b = bp >> 2;
  int n0 = blockIdx.x * 128, m0 = blockIdx.y * 128;
  int t = threadIdx.x;
  int lane = t & 63;
  int w = t >> 6;
  int wm = w >> 1, wn = w & 1;
  int lr = lane & 15, quad = lane >> 4;
  int rowL = t >> 2;            // 0..63
  int colL = (t & 3) * 8;       // 0,8,16,24
  int ldsoff = (t & ~63) * 8;   // wave-uniform LDS base (ushort units)

  const ushort_t* A1 = Aprev + (size_t)bp * (F_ * N_) + (size_t)(m0 + rowL) * N_ + colL;
  const ushort_t* B1 = Bt + (size_t)bp * N_ * N_ + (size_t)(n0 + rowL) * N_ + colL;
  const ushort_t* A2 = fwbf + (size_t)p * (F_ * KG_) + (size_t)(m0 + rowL) * KG_ +
                       kslice * G_ + colL;
  const ushort_t* B2 = xT + (size_t)b * (N_ * G_) + (size_t)(n0 + rowL) * G_ + colL;

  f32x4 acc[4][4] = {};

  if (has_prev) {
    for (int kt = 0; kt < N_; kt += 64) {
      __syncthreads();
      gload_lds16(A1 + kt, &As[0][ldsoff]);
      gload_lds16(A1 + (size_t)64 * N_ + kt, &As[0][2048 + ldsoff]);
      gload_lds16(A1 + kt + 32, &As[1][ldsoff]);
      gload_lds16(A1 + (size_t)64 * N_ + kt + 32, &As[1][2048 + ldsoff]);
      gload_lds16(B1 + kt, &Bs[0][ldsoff]);
      gload_lds16(B1 + (size_t)64 * N_ + kt, &Bs[0][2048 + ldsoff]);
      gload_lds16(B1 + kt + 32, &Bs[1][ldsoff]);
      gload_lds16(B1 + (size_t)64 * N_ + kt + 32, &Bs[1][2048 + ldsoff]);
      __syncthreads();
#pragma unroll
      for (int c = 0; c < 2; ++c) {
        bf16x8 af[4], bfr[4];
#pragma unroll
        for (int mi = 0; mi < 4; ++mi)
          af[mi] = __builtin_bit_cast(bf16x8,
              *(const u16x8*)&As[c][(wm * 64 + mi * 16 + lr) * 32 + quad * 8]);
#pragma unroll
        for (int ni = 0; ni < 4; ++ni)
          bfr[ni] = __builtin_bit_cast(bf16x8,
              *(const u16x8*)&Bs[c][(wn * 64 + ni * 16 + lr) * 32 + quad * 8]);
#pragma unroll
        for (int mi = 0; mi < 4; ++mi)
#pragma unroll
          for (int ni = 0; ni < 4; ++ni)
            acc[mi][ni] = __builtin_amdgcn_mfma_f32_16x16x32_bf16(af[mi], bfr[ni], acc[mi][ni], 0, 0, 0);
      }
    }
  }
  for (int gt = 0; gt < G_; gt += 64) {
    __syncthreads();
    gload_lds16(A2 + gt, &As[0][ldsoff]);
    gload_lds16(A2 + (size_t)64 * KG_ + gt, &As[0][2048 + ldsoff]);
    gload_lds16(A2 + gt + 32, &As[1][ldsoff]);
    gload_lds16(A2 + (size_t)64 * KG_ + gt + 32, &As[1][2048 + ldsoff]);
    gload_lds16(B2 + gt, &Bs[0][ldsoff]);
    gload_lds16(B2 + (size_t)64 * G_ + gt, &Bs[0][2048 + ldsoff]);
    gload_lds16(B2 + gt + 32, &Bs[1][ldsoff]);
    gload_lds16(B2 + (size_t)64 * G_ + gt + 32, &Bs[1][2048 + ldsoff]);
    __syncthreads();
#pragma unroll
    for (int c = 0; c < 2; ++c) {
      bf16x8 af[4], bfr[4];
#pragma unroll
      for (int mi = 0; mi < 4; ++mi)
        af[mi] = __builtin_bit_cast(bf16x8,
            *(const u16x8*)&As[c][(wm * 64 + mi * 16 + lr) * 32 + quad * 8]);
#pragma unroll
      for (int ni = 0; ni < 4; ++ni)
        bfr[ni] = __builtin_bit_cast(bf16x8,
            *(const u16x8*)&Bs[c][(wn * 64 + ni * 16 + lr) * 32 + quad * 8]);
#pragma unroll
      for (int mi = 0; mi < 4; ++mi)
#pragma unroll
        for (int ni = 0; ni < 4; ++ni)
          acc[mi][ni] = __builtin_amdgcn_mfma_f32_16x16x32_bf16(af[mi], bfr[ni], acc[mi][ni], 0, 0, 0);
    }
  }

  if (last) {
    float* Ob = outf + (size_t)bp * (F_ * N_);
#pragma unroll
    for (int mi = 0; mi < 4; ++mi) {
      int fbase = m0 + wm * 64 + mi * 16 + quad * 4;
#pragma unroll
      for (int ni = 0; ni < 4; ++ni) {
        int n = n0 + wn * 64 + ni * 16 + lr;
#pragma unroll
        for (int r = 0; r < 4; ++r) {
          float v = acc[mi][ni][r] + bias[fbase + r];
          Ob[(size_t)(fbase + r) * N_ + n] = v >= 0.f ? v : 0.01f * v;
        }
      }
    }
  } else {
    ushort_t* Ob = outb + (size_t)bp * (F_ * N_);
    float iv[4];
#pragma unroll
    for (int ni = 0; ni < 4; ++ni)
      iv[ni] = 1.0f / sumb[(size_t)bp * N_ + n0 + wn * 64 + ni * 16 + lr];
#pragma unroll
    for (int mi = 0; mi < 4; ++mi) {
      int fbase = m0 + wm * 64 + mi * 16 + quad * 4;
#pragma unroll
      for (int ni = 0; ni < 4; ++ni) {
        int n = n0 + wn * 64 + ni * 16 + lr;
#pragma unroll
        for (int r = 0; r < 4; ++r)
          Ob[(size_t)(fbase + r) * N_ + n] = f2bf(acc[mi][ni][r] * iv[ni]);
      }
    }
  }
}

// ---------------------------------------------------------------------------
extern "C" void kernel_launch(void* const* d_in, const int* in_sizes, int n_in,
                              void* d_out, int out_size, void* d_ws, size_t ws_size,
                              hipStream_t stream) {
  const float* x = (const float*)d_in[0];
  const float* mixer = (const float*)d_in[1];
  const float* weight = (const float*)d_in[2];
  const float* wb = (const float*)d_in[3];
  const float* fw = (const float*)d_in[4];
  const float* bias = (const float*)d_in[5];
  const float* S = (const float*)d_in[6];
  float* out = (float*)d_out;

  char* ws = (char*)d_ws;
  size_t off = 0;
  auto take = [&](size_t bytes) -> char* {
    char* p = ws + off;
    off = (off + bytes + 255) & ~(size_t)255;
    return p;
  };
  float* e1 = (float*)take((size_t)B_ * P_ * N_ * 4);
  float* e2 = (float*)take((size_t)B_ * P_ * N_ * 4);
  float* sumb = (float*)take((size_t)B_ * P_ * N_ * 4);
  ushort_t* fwbf = (ushort_t*)take((size_t)P_ * F_ * KHOP * G_ * 2);
  ushort_t* xT = (ushort_t*)take((size_t)B_ * N_ * G_ * 2);
  ushort_t* expT = (ushort_t*)take((size_t)B_ * P_ * N_ * N_ * 2);
  ushort_t* sA = (ushort_t*)take((size_t)B_ * P_ * F_ * N_ * 2);
  ushort_t* sB = (ushort_t*)take((size_t)B_ * P_ * F_ * N_ * 2);

  k_prep<<<1792, 256, 0, stream>>>(x, mixer, weight, wb, fw, e1, e2, fwbf, xT, sumb);
  k_att<<<dim3(4, 16, 32), 256, 0, stream>>>(e1, e2, S, expT, sumb);

  dim3 gg(8, 2, 32);
  // Horner (1/rowsum folded into stored intermediates):
  // s3' = (fw3*x) . inv ; s2' = (s3'*E^T + fw2*x) . inv ;
  // s1' = (s2'*E^T + fw1*x) . inv ; out = lrelu(s1'*E^T + fw0*x + bias)
  gemm_step<<<gg, 256, 0, stream>>>(nullptr, expT, fwbf, xT, bias, sumb, sA, nullptr, 3, 0, 0);
  gemm_step<<<gg, 256, 0, stream>>>(sA, expT, fwbf, xT, bias, sumb, sB, nullptr, 2, 1, 0);
  gemm_step<<<gg, 256, 0, stream>>>(sB, expT, fwbf, xT, bias, sumb, sA, nullptr, 1, 1, 0);
  gemm_step<<<gg, 256, 0, stream>>>(sA, expT, fwbf, xT, bias, sumb, nullptr, out, 0, 1, 1);
}